// Round 14
// baseline (5233.004 us; speedup 1.0000x reference)
//
#include <hip/hip_runtime.h>
#include <cstddef>

// WordEncoder: emb gather -> masked LSTM (T=1024) -> relu(h@Wd+bd)
// R14: TWO recurrence chains per block, software-interleaved (deterministic
// anti-phase). 256 blocks = 8 pair-groups x 32 unit-groups, 1/CU. Each block
// owns 8 units for 16 batches (chains A,B of 8 batches each; one shared
// 96-VGPR weight slice). Phase A's exchange RT hides under phase B's
// compute and vice versa; each phase pre-issues the NEXT phase's packet
// loads so resolve is a first-try tag hit. Exchange protocol = R8 exactly:
// (tag|h) u64 packets dual-published (workgroup->XCD-L2 + agent->IC),
// bounded L2 retry -> sticky IC fallback; tags validate every value
// (placement-independent); zero-init/replay-alias benign (deterministic).

typedef unsigned int u32x4 __attribute__((ext_vector_type(4)));

constexpr int TLEN = 1024;
constexpr int EDIM = 128;
constexpr int UDIM = 256;
constexpr int DDIM = 256;

constexpr int BPB  = 8;    // batches per chain per block
constexpr int UPB  = 8;    // units per block
constexpr int ZCOL = 32;   // z cols per block (4 gates x 8 units)
constexpr int HXROW = 432; // (384/32)*36 padded row
constexpr int ZROW = 36;   // 32 + 4 pad

__device__ unsigned long long g_pktA[2][128][256]; // XCD-local path (L2)
__device__ unsigned long long g_pktB[2][128][256]; // device-coherent mirror (IC)

__device__ __forceinline__ int pidx(int k) { return ((k >> 5) * 36) + (k & 31); }

__device__ __forceinline__ u32x4 pkt_load_ic(const unsigned long long* p) {
  u32x4 v;
  asm volatile("global_load_dwordx4 %0, %1, off sc0 sc1" : "=v"(v) : "v"(p));
  return v;
}
__device__ __forceinline__ u32x4 pkt_load_l2(const unsigned long long* p) {
  u32x4 v; // sc0: bypass L1, hit the XCD-coherent L2
  asm volatile("global_load_dwordx4 %0, %1, off sc0" : "=v"(v) : "v"(p));
  return v;
}
#define PKT_WAIT4(a, b, c, d) \
  asm volatile("s_waitcnt vmcnt(0)" : "+v"(a), "+v"(b), "+v"(c), "+v"(d) :: "memory")
#define TAGS_OK() \
  ((p0[1] == want) & (p0[3] == want) & (p1[1] == want) & (p1[3] == want) & \
   (p2[1] == want) & (p2[3] == want) & (p3[1] == want) & (p3[3] == want))

// Sum across the 16-lane DPP row (ksl groups == DPP rows). Pure VALU pipe.
__device__ __forceinline__ float rowsum16(float v) {
  v += __int_as_float(
      __builtin_amdgcn_mov_dpp(__float_as_int(v), 0x121, 0xf, 0xf, true));
  v += __int_as_float(
      __builtin_amdgcn_mov_dpp(__float_as_int(v), 0x122, 0xf, 0xf, true));
  v += __int_as_float(
      __builtin_amdgcn_mov_dpp(__float_as_int(v), 0x124, 0xf, 0xf, true));
  v += __int_as_float(
      __builtin_amdgcn_mov_dpp(__float_as_int(v), 0x128, 0xf, 0xf, true));
  return v;
}

__global__ __launch_bounds__(256, 1) void we_lstm(
    const int* __restrict__ tokens, const float* __restrict__ emb,
    const float* __restrict__ Wk, const float* __restrict__ Wr,
    const float* __restrict__ bz, float* __restrict__ out)
{
  __shared__ float hx[2][BPB][HXROW]; // [chain][batch][h(256)|x(128)], padded
  __shared__ float zs[BPB][ZROW];     // reduced z (shared across phases; safe)
  __shared__ float bias_s[ZCOL];

  const int tid = threadIdx.x;
  const int bid = blockIdx.x;
  const int pg  = bid & 7;   // 32 blocks sharing pg -> one XCD (round-robin)
  const int ug  = bid >> 3;  // [0,32)
  const int b0A = pg * 16;
  const int b0B = pg * 16 + 8;
  const int u0  = ug * UPB;

  // GEMM decomposition: 256 = 2 row-halves x 8 col-quads x 16 k-slices;
  // 4 batch rows/thread. k = ksl*4 + i*64 + j ; i<4 h-part, i>=4 x-part.
  const int ksl = tid & 15;
  const int cq  = (tid >> 4) & 7;
  const int bh  = tid >> 7;

  // ---- prologue: weight slice into registers (24k x 4c per thread) ----
  float w[96];
#pragma unroll
  for (int i = 0; i < 6; ++i)
#pragma unroll
    for (int j = 0; j < 4; ++j) {
      const int k = ksl * 4 + i * 64 + j;
#pragma unroll
      for (int cc = 0; cc < 4; ++cc) {
        const int c   = cq * 4 + cc;
        const int col = ((c >> 3) << 8) + u0 + (c & 7);
        w[(i * 4 + j) * 4 + cc] =
            (k < UDIM) ? Wr[k * 1024 + col] : Wk[(k - UDIM) * 1024 + col];
      }
    }
  if (tid < ZCOL) bias_s[tid] = bz[((tid >> 3) << 8) + u0 + (tid & 7)];

  float cregA = 0.f, cregB = 0.f;
  const int gb = tid >> 3, gu = tid & 7;         // gates (tid<64)
  const int xb = tid >> 5, xe = (tid & 31) << 2; // x stage
  const int up = tid & 127, bq = (tid >> 7) * 4; // pkt stage

  bool use_local = true; // self-tuning exchange path (sticky downgrade)

  // ---- prefetch step 0 x and gate-tokens for both chains ----
  float4 xvA = *(const float4*)&emb[(size_t)tokens[(b0A + xb) * TLEN] * EDIM + xe];
  float4 xvB = *(const float4*)&emb[(size_t)tokens[(b0B + xb) * TLEN] * EDIM + xe];
  int tkA = (tid < 64) ? tokens[(b0A + gb) * TLEN] : 1;
  int tkB = (tid < 64) ? tokens[(b0B + gb) * TLEN] : 1;

  u32x4 pA0, pA1, pA2, pA3, pB0, pB1, pB2, pB3;

  // One LSTM step for one chain. Pre-issued packets (p0..p3) are resolved at
  // entry; next phase's loads (q0..q3, chain at b0n, step itn) are issued
  // after the GEMM so their RT hides under reduce+gates+publish.
  auto run_phase = [&](const int b0c, float (*hxc)[HXROW], float& creg,
                       int& tk_g, float4& xv,
                       u32x4& p0, u32x4& p1, u32x4& p2, u32x4& p3,
                       const int b0n,
                       u32x4& q0, u32x4& q1, u32x4& q2, u32x4& q3,
                       const int it, const int itn) {
    const int rp = (it + 1) & 1;        // packets of h(it-1) live in slot (it-1)&1
    const unsigned want = (unsigned)it; // producer tag = step+1
    const int ho = pidx(2 * up);

    // ---- resolve pre-issued packets + stage h ----
    if (it > 0) {
      PKT_WAIT4(p0, p1, p2, p3);
      bool ok = TAGS_OK();
      if (!ok && use_local) {
        int rounds = 0;
        do {
          __builtin_amdgcn_s_sleep(1);
          p0 = pkt_load_l2(&g_pktA[rp][b0c + bq + 0][2 * up]);
          p1 = pkt_load_l2(&g_pktA[rp][b0c + bq + 1][2 * up]);
          p2 = pkt_load_l2(&g_pktA[rp][b0c + bq + 2][2 * up]);
          p3 = pkt_load_l2(&g_pktA[rp][b0c + bq + 3][2 * up]);
          PKT_WAIT4(p0, p1, p2, p3);
          ok = TAGS_OK();
        } while (!ok && ++rounds < 16);
        if (!ok) use_local = false; // cross-XCD placement: downgrade for good
      }
      while (!ok) {
        p0 = pkt_load_ic(&g_pktB[rp][b0c + bq + 0][2 * up]);
        p1 = pkt_load_ic(&g_pktB[rp][b0c + bq + 1][2 * up]);
        p2 = pkt_load_ic(&g_pktB[rp][b0c + bq + 2][2 * up]);
        p3 = pkt_load_ic(&g_pktB[rp][b0c + bq + 3][2 * up]);
        PKT_WAIT4(p0, p1, p2, p3);
        ok = TAGS_OK();
        if (!ok) __builtin_amdgcn_s_sleep(1);
      }
      *(float2*)&hxc[bq + 0][ho] =
          make_float2(__uint_as_float(p0[0]), __uint_as_float(p0[2]));
      *(float2*)&hxc[bq + 1][ho] =
          make_float2(__uint_as_float(p1[0]), __uint_as_float(p1[2]));
      *(float2*)&hxc[bq + 2][ho] =
          make_float2(__uint_as_float(p2[0]), __uint_as_float(p2[2]));
      *(float2*)&hxc[bq + 3][ho] =
          make_float2(__uint_as_float(p3[0]), __uint_as_float(p3[2]));
    } else {
#pragma unroll
      for (int jj = 0; jj < 4; ++jj)
        *(float2*)&hxc[bq + jj][ho] = make_float2(0.f, 0.f);
    }
    *(float4*)&hxc[xb][pidx(UDIM + xe)] = xv;
    __syncthreads(); // stage barrier: h+x ready

    // ---- full GEMM (h-part i=0..3, x-part i=4,5) ----
    float acc[4][4];
#pragma unroll
    for (int r = 0; r < 4; ++r) {
      acc[r][0] = 0.f; acc[r][1] = 0.f; acc[r][2] = 0.f; acc[r][3] = 0.f;
    }
#pragma unroll
    for (int i = 0; i < 6; ++i) {
      const int hoff = pidx(ksl * 4 + i * 64);
      float4 hv[4];
#pragma unroll
      for (int r = 0; r < 4; ++r)
        hv[r] = *(const float4*)&hxc[bh * 4 + r][hoff];
#pragma unroll
      for (int j = 0; j < 4; ++j)
#pragma unroll
        for (int r = 0; r < 4; ++r) {
          const float hval = (j == 0) ? hv[r].x : (j == 1) ? hv[r].y
                             : (j == 2) ? hv[r].z : hv[r].w;
#pragma unroll
          for (int cc = 0; cc < 4; ++cc)
            acc[r][cc] += hval * w[(i * 4 + j) * 4 + cc];
        }
    }

    // ---- pre-issue NEXT phase's packet loads (RT hides under the tail) ----
    if (itn > 0 && itn < TLEN) {
      const int rpn = (itn + 1) & 1;
      if (use_local) {
        q0 = pkt_load_l2(&g_pktA[rpn][b0n + bq + 0][2 * up]);
        q1 = pkt_load_l2(&g_pktA[rpn][b0n + bq + 1][2 * up]);
        q2 = pkt_load_l2(&g_pktA[rpn][b0n + bq + 2][2 * up]);
        q3 = pkt_load_l2(&g_pktA[rpn][b0n + bq + 3][2 * up]);
      } else {
        q0 = pkt_load_ic(&g_pktB[rpn][b0n + bq + 0][2 * up]);
        q1 = pkt_load_ic(&g_pktB[rpn][b0n + bq + 1][2 * up]);
        q2 = pkt_load_ic(&g_pktB[rpn][b0n + bq + 2][2 * up]);
        q3 = pkt_load_ic(&g_pktB[rpn][b0n + bq + 3][2 * up]);
      }
    }

    // ---- prefetch this chain's next x / gate-token ----
    float4 xv_n;
    int tk_n = 1;
    if (it + 1 < TLEN) {
      const int tk_x = tokens[(b0c + xb) * TLEN + it + 1];
      xv_n = *(const float4*)&emb[(size_t)tk_x * EDIM + xe];
      if (tid < 64) tk_n = tokens[(b0c + gb) * TLEN + it + 1];
    }

    // ---- k-reduce via DPP row_ror (VALU pipe) ----
#pragma unroll
    for (int r = 0; r < 4; ++r)
#pragma unroll
      for (int cc = 0; cc < 4; ++cc)
        acc[r][cc] = rowsum16(acc[r][cc]);
    if (ksl == 0) {
#pragma unroll
      for (int r = 0; r < 4; ++r)
        *(float4*)&zs[bh * 4 + r][cq * 4] =
            make_float4(acc[r][0], acc[r][1], acc[r][2], acc[r][3]);
    }
    __syncthreads(); // zs ready

    // ---- gates + publish (wave 0 only; no drains -- R8 protocol) ----
    if (tid < 64) {
      const float zi = zs[gb][gu]      + bias_s[gu];
      const float zf = zs[gb][8 + gu]  + bias_s[8 + gu];
      const float zg = zs[gb][16 + gu] + bias_s[16 + gu];
      const float zo = zs[gb][24 + gu] + bias_s[24 + gu];
      const float gi = 1.f / (1.f + __expf(-zi));
      const float gf = 1.f / (1.f + __expf(-zf));
      const float gg = 1.f - 2.f / (1.f + __expf(2.f * zg)); // tanh
      const float go = 1.f / (1.f + __expf(-zo));
      const float cn = gf * creg + gi * gg;
      const float th = 1.f - 2.f / (1.f + __expf(2.f * cn));
      const float hn = go * th;
      const bool msk = (tk_g != 0);
      const float hold = hxc[gb][pidx(u0 + gu)];
      const float h2 = msk ? hn : hold;
      creg = msk ? cn : creg;
      const unsigned long long pkt =
          ((unsigned long long)(unsigned)(it + 1) << 32) | __float_as_uint(h2);
      __hip_atomic_store(&g_pktA[it & 1][b0c + gb][u0 + gu], pkt,
                         __ATOMIC_RELAXED, __HIP_MEMORY_SCOPE_WORKGROUP);
      __hip_atomic_store(&g_pktB[it & 1][b0c + gb][u0 + gu], pkt,
                         __ATOMIC_RELAXED, __HIP_MEMORY_SCOPE_AGENT);
      __builtin_nontemporal_store(
          h2, &out[((size_t)(b0c + gb) * TLEN + it) * DDIM + u0 + gu]);
    }
    xv = xv_n;
    tk_g = tk_n;
    // no end barrier: the next phase uses the other hx buffer; zs is next
    // written only after that phase's stage barrier (wave 0 participates).
  };

  for (int it = 0; it < TLEN; ++it) {
    // phase A (step it); pre-issues B's loads for step it
    run_phase(b0A, hx[0], cregA, tkA, xvA, pA0, pA1, pA2, pA3,
              b0B, pB0, pB1, pB2, pB3, it, it);
    // phase B (step it); pre-issues A's loads for step it+1
    run_phase(b0B, hx[1], cregB, tkB, xvB, pB0, pB1, pB2, pB3,
              b0A, pA0, pA1, pA2, pA3, it, it + 1);
  }
}

// y = relu(H @ Wd + bd), in place over d_out (h history -> y). 32 rows/block.
__global__ __launch_bounds__(256, 2) void we_proj(
    const float* __restrict__ Wd, const float* __restrict__ bd,
    float* __restrict__ out)
{
  __shared__ float hs[32][260];
  __shared__ float ws[32][260];
  __shared__ float bds[DDIM];

  const int tid = threadIdx.x;
  const size_t row0 = (size_t)blockIdx.x * 32;

#pragma unroll
  for (int j2 = 0; j2 < 8; ++j2) {
    const int idx = tid + j2 * 256;
    const int r = idx >> 6;
    const int cq = idx & 63;
    *(float4*)&hs[r][cq * 4] = *(const float4*)&out[(row0 + r) * DDIM + cq * 4];
  }
  bds[tid] = bd[tid];

  const int rg = tid >> 5;
  const int c0 = (tid & 31) * 8;
  float acc[4][8];
#pragma unroll
  for (int i = 0; i < 4; ++i)
#pragma unroll
    for (int c = 0; c < 8; ++c) acc[i][c] = 0.f;

  for (int kt = 0; kt < 8; ++kt) {
    __syncthreads();
#pragma unroll
    for (int j2 = 0; j2 < 8; ++j2) {
      const int idx = tid + j2 * 256;
      const int kk = idx >> 6;
      const int cq = idx & 63;
      *(float4*)&ws[kk][cq * 4] =
          *(const float4*)&Wd[(size_t)(kt * 32 + kk) * DDIM + cq * 4];
    }
    __syncthreads();
#pragma unroll
    for (int kk = 0; kk < 32; ++kk) {
      const float4 wv0 = *(const float4*)&ws[kk][c0];
      const float4 wv1 = *(const float4*)&ws[kk][c0 + 4];
#pragma unroll
      for (int i = 0; i < 4; ++i) {
        const float hval = hs[rg + i * 8][kt * 32 + kk];
        acc[i][0] += hval * wv0.x; acc[i][1] += hval * wv0.y;
        acc[i][2] += hval * wv0.z; acc[i][3] += hval * wv0.w;
        acc[i][4] += hval * wv1.x; acc[i][5] += hval * wv1.y;
        acc[i][6] += hval * wv1.z; acc[i][7] += hval * wv1.w;
      }
    }
  }
#pragma unroll
  for (int i = 0; i < 4; ++i) {
    float4 y0, y1;
    y0.x = fmaxf(acc[i][0] + bds[c0 + 0], 0.f);
    y0.y = fmaxf(acc[i][1] + bds[c0 + 1], 0.f);
    y0.z = fmaxf(acc[i][2] + bds[c0 + 2], 0.f);
    y0.w = fmaxf(acc[i][3] + bds[c0 + 3], 0.f);
    y1.x = fmaxf(acc[i][4] + bds[c0 + 4], 0.f);
    y1.y = fmaxf(acc[i][5] + bds[c0 + 5], 0.f);
    y1.z = fmaxf(acc[i][6] + bds[c0 + 6], 0.f);
    y1.w = fmaxf(acc[i][7] + bds[c0 + 7], 0.f);
    const size_t orow = (row0 + rg + i * 8) * DDIM;
    *(float4*)&out[orow + c0]     = y0;
    *(float4*)&out[orow + c0 + 4] = y1;
  }
}

extern "C" void kernel_launch(void* const* d_in, const int* in_sizes, int n_in,
                              void* d_out, int out_size, void* d_ws, size_t ws_size,
                              hipStream_t stream) {
  const int*   tokens = (const int*)d_in[0];
  const float* emb    = (const float*)d_in[1];
  const float* Wk     = (const float*)d_in[2];
  const float* Wr     = (const float*)d_in[3];
  const float* bz     = (const float*)d_in[4];
  const float* Wd     = (const float*)d_in[5];
  const float* bd     = (const float*)d_in[6];
  float* out = (float*)d_out;
  (void)in_sizes; (void)n_in; (void)out_size; (void)d_ws; (void)ws_size;
  hipLaunchKernelGGL(we_lstm, dim3(256), dim3(256), 0, stream,
                     tokens, emb, Wk, Wr, bz, out);
  hipLaunchKernelGGL(we_proj, dim3(128 * TLEN / 32), dim3(256), 0, stream,
                     Wd, bd, out);
}